// Round 4
// baseline (315.733 us; speedup 1.0000x reference)
//
#include <hip/hip_runtime.h>
#include <stdint.h>

#define NB 4096
#define TT 64
#define CC 128
#define HH 64
#define BPB 4          // batch elements per block; grid = NB/BPB = 1024 = 4 blocks/CU resident
#define QSTR 72        // q/k/vT LDS row stride: 64 + 8 pad (144 B rows, 16B-aligned)

typedef __bf16 bf16x8 __attribute__((ext_vector_type(8)));
typedef float f32x4 __attribute__((ext_vector_type(4)));

__device__ __forceinline__ unsigned short f2bf(float f) {
  union { float f; uint32_t u; } a; a.f = f;
  uint32_t u = a.u;
  u += 0x7fffu + ((u >> 16) & 1u);   // round-to-nearest-even
  return (unsigned short)(u >> 16);
}

// Pre-swizzle the three [C,H] fp32 weight matrices into MFMA B-fragment order:
// wz[((mat*4 + nt)*4 + ks)*64 + lane] holds the 8 bf16 B-elements lane needs for
// that (nt, ks) MFMA: W^T[h = nt*16 + (lane&15)][c = ks*32 + (lane>>4)*8 + j].
// Lane-contiguous 16B -> attn kernel loads are perfectly coalesced L2 hits.
__global__ void swizzle_w_kernel(const float* __restrict__ Wq,
                                 const float* __restrict__ Wk,
                                 const float* __restrict__ Wv,
                                 unsigned short* __restrict__ wz) {
  int i = blockIdx.x * 256 + threadIdx.x;   // [0, 3*16*64)
  if (i >= 3 * 16 * 64) return;
  int mat  = i >> 10;          // /1024
  int rem  = i & 1023;
  int frag = rem >> 6;         // (nt*4 + ks)
  int lane = rem & 63;
  int nt = frag >> 2, ks = frag & 3;
  int quad = lane >> 4, l15 = lane & 15;
  int h  = nt * 16 + l15;
  int c0 = ks * 32 + quad * 8;
  const float* W = (mat == 0) ? Wq : (mat == 1) ? Wk : Wv;
  unsigned short* o = wz + (size_t)i * 8;
  #pragma unroll
  for (int j = 0; j < 8; ++j) o[j] = f2bf(W[(c0 + j) * HH + h]);
}

__global__ __launch_bounds__(256, 4)
void attn_kernel(const float* __restrict__ x,
                 const unsigned short* __restrict__ wz,
                 float* __restrict__ out) {
  __shared__ unsigned short qs[64 * QSTR];   // q rows; reused for P (wave-local rows)
  __shared__ unsigned short ks_[64 * QSTR];  // k row-major [t][h]
  __shared__ unsigned short vts[64 * QSTR];  // v transposed [h][t]

  const int tid  = threadIdx.x;
  const int wave = tid >> 6;
  const int lane = tid & 63;
  const int quad = lane >> 4;
  const int l15  = lane & 15;
  const int mbase = wave * 16;   // this wave's row tile
  const float scale = 0.08838834764831845f;  // 128^-0.5 (embed dim, per reference)

  const int b0 = blockIdx.x * BPB;

  for (int bi = 0; bi < BPB; ++bi) {
    const int b = b0 + bi;

    // ---- x A-fragments: A[m=l15][k=quad*8+j], k = ksi*32 + quad*8 + j.
    // Global loads issued before the reuse-barrier (independent of LDS).
    bf16x8 xfrag[4];
    {
      const float* xr = x + ((size_t)b * TT + mbase + l15) * CC + quad * 8;
      #pragma unroll
      for (int ksi = 0; ksi < 4; ++ksi) {
        f32x4 lo = *(const f32x4*)(xr + ksi * 32);
        f32x4 hi = *(const f32x4*)(xr + ksi * 32 + 4);
        bf16x8 f;
        #pragma unroll
        for (int j = 0; j < 4; ++j) {
          union { unsigned short u; __bf16 b; } cv;
          cv.u = f2bf(lo[j]); f[j] = cv.b;
          cv.u = f2bf(hi[j]); f[j + 4] = cv.b;
        }
        xfrag[ksi] = f;
      }
    }

    if (bi > 0) __syncthreads();   // previous batch's LDS reads must finish

    // ---- Phase 1: q, k, v projections; B-fragments straight from global (L2)
    #pragma unroll
    for (int mat = 0; mat < 3; ++mat) {
      const unsigned short* wm = wz + mat * (16 * 64 * 8);
      #pragma unroll
      for (int nt = 0; nt < 4; ++nt) {
        f32x4 acc = {0.f, 0.f, 0.f, 0.f};
        #pragma unroll
        for (int ksi = 0; ksi < 4; ++ksi) {
          bf16x8 bfrag = *(const bf16x8*)(wm + (((nt * 4 + ksi) * 64) + lane) * 8);
          acc = __builtin_amdgcn_mfma_f32_16x16x32_bf16(xfrag[ksi], bfrag, acc, 0, 0, 0);
        }
        // C/D: col = nt*16 + l15, row = mbase + quad*4 + r
        #pragma unroll
        for (int r = 0; r < 4; ++r) {
          int row = mbase + quad * 4 + r;
          int col = nt * 16 + l15;
          unsigned short v = f2bf(acc[r]);
          if (mat == 0)      qs[row * QSTR + col] = v;
          else if (mat == 1) ks_[row * QSTR + col] = v;
          else               vts[col * QSTR + row] = v;   // v stored transposed
        }
      }
    }
    __syncthreads();   // k, vT (cross-wave) ready

    // ---- Phase 2: S = q k^T * scale, causal mask, softmax -> P into qs (wave-local)
    f32x4 sc[4];
    {
      bf16x8 aq[2];
      #pragma unroll
      for (int k2 = 0; k2 < 2; ++k2)
        aq[k2] = *(const bf16x8*)(&qs[(mbase + l15) * QSTR + k2 * 32 + quad * 8]);
      #pragma unroll
      for (int nt = 0; nt < 4; ++nt) {
        f32x4 acc = {0.f, 0.f, 0.f, 0.f};
        #pragma unroll
        for (int k2 = 0; k2 < 2; ++k2) {
          bf16x8 bk = *(const bf16x8*)(&ks_[(nt * 16 + l15) * QSTR + k2 * 32 + quad * 8]);
          acc = __builtin_amdgcn_mfma_f32_16x16x32_bf16(aq[k2], bk, acc, 0, 0, 0);
        }
        sc[nt] = acc;
      }
    }
    #pragma unroll
    for (int r = 0; r < 4; ++r) {
      int row = mbase + quad * 4 + r;
      float vals[4];
      #pragma unroll
      for (int nt = 0; nt < 4; ++nt) {
        int col = nt * 16 + l15;
        float v = sc[nt][r] * scale;
        vals[nt] = (col <= row) ? v : -__builtin_inff();
      }
      float m = fmaxf(fmaxf(vals[0], vals[1]), fmaxf(vals[2], vals[3]));
      #pragma unroll
      for (int d = 1; d < 16; d <<= 1) m = fmaxf(m, __shfl_xor(m, d, 64));
      float s = 0.f;
      #pragma unroll
      for (int nt = 0; nt < 4; ++nt) { vals[nt] = __expf(vals[nt] - m); s += vals[nt]; }
      #pragma unroll
      for (int d = 1; d < 16; d <<= 1) s += __shfl_xor(s, d, 64);
      float inv = 1.f / s;
      // P rows overwrite this wave's own q rows — only this wave ever reads them,
      // and the write is data-dependent on the q reads above: no barrier needed.
      #pragma unroll
      for (int nt = 0; nt < 4; ++nt)
        qs[row * QSTR + nt * 16 + l15] = f2bf(vals[nt] * inv);
    }

    // ---- Phase 3: O = P @ V (A = P from qs, wave-local rows; B = vT, synced above)
    bf16x8 ap[2];
    #pragma unroll
    for (int k2 = 0; k2 < 2; ++k2)
      ap[k2] = *(const bf16x8*)(&qs[(mbase + l15) * QSTR + k2 * 32 + quad * 8]);
    float* ob = out + ((size_t)b * TT) * HH;
    #pragma unroll
    for (int nt = 0; nt < 4; ++nt) {
      f32x4 acc = {0.f, 0.f, 0.f, 0.f};
      #pragma unroll
      for (int k2 = 0; k2 < 2; ++k2) {
        bf16x8 bv = *(const bf16x8*)(&vts[(nt * 16 + l15) * QSTR + k2 * 32 + quad * 8]);
        acc = __builtin_amdgcn_mfma_f32_16x16x32_bf16(ap[k2], bv, acc, 0, 0, 0);
      }
      #pragma unroll
      for (int r = 0; r < 4; ++r) {
        int row = mbase + quad * 4 + r;
        ob[row * HH + nt * 16 + l15] = acc[r];   // fp32 store
      }
    }
  }
}

extern "C" void kernel_launch(void* const* d_in, const int* in_sizes, int n_in,
                              void* d_out, int out_size, void* d_ws, size_t ws_size,
                              hipStream_t stream) {
  const float* x  = (const float*)d_in[0];
  const float* Wq = (const float*)d_in[1];
  const float* Wk = (const float*)d_in[2];
  const float* Wv = (const float*)d_in[3];
  unsigned short* wz = (unsigned short*)d_ws;   // 3*16*64*8 bf16 = 48 KiB scratch
  float* outp = (float*)d_out;

  swizzle_w_kernel<<<(3 * 16 * 64 + 255) / 256, 256, 0, stream>>>(Wq, Wk, Wv, wz);
  attn_kernel<<<NB / BPB, 256, 0, stream>>>(x, wz, outp);
}

// Round 5
// 223.126 us; speedup vs baseline: 1.4150x; 1.4150x over previous
//
#include <hip/hip_runtime.h>
#include <stdint.h>

#define NB 4096
#define TT 64
#define CC 128
#define HH 64
#define BPB 4          // batches per block; grid = 1024 = 2 blocks/CU x 256 CU x 2... exactly resident
#define QSTR 72        // q/k/vT LDS row stride: 64 + 8 pad (144 B rows; (l15+quad)%8 bank spread)

typedef __bf16 bf16x8 __attribute__((ext_vector_type(8)));
typedef float f32x4 __attribute__((ext_vector_type(4)));

__device__ __forceinline__ unsigned short f2bf(float f) {
  union { float f; uint32_t u; } a; a.f = f;
  uint32_t u = a.u;
  u += 0x7fffu + ((u >> 16) & 1u);   // round-to-nearest-even
  return (unsigned short)(u >> 16);
}

// Pre-swizzle the three [C,H] fp32 weight matrices into MFMA B-fragment order:
// wz[((mat*4 + nt)*4 + ks)*64 + lane][8] = W^T[h = nt*16 + (lane&15)][c = ks*32 + (lane>>4)*8 + j]
__global__ void swizzle_w_kernel(const float* __restrict__ Wq,
                                 const float* __restrict__ Wk,
                                 const float* __restrict__ Wv,
                                 unsigned short* __restrict__ wz) {
  int i = blockIdx.x * 256 + threadIdx.x;   // [0, 3*16*64)
  if (i >= 3 * 16 * 64) return;
  int mat  = i >> 10;
  int rem  = i & 1023;
  int frag = rem >> 6;         // nt*4 + ks
  int lane = rem & 63;
  int nt = frag >> 2, ks = frag & 3;
  int quad = lane >> 4, l15 = lane & 15;
  int h  = nt * 16 + l15;
  int c0 = ks * 32 + quad * 8;
  const float* W = (mat == 0) ? Wq : (mat == 1) ? Wk : Wv;
  unsigned short* o = wz + (size_t)i * 8;
  #pragma unroll
  for (int j = 0; j < 8; ++j) o[j] = f2bf(W[(c0 + j) * HH + h]);
}

__global__ __launch_bounds__(256, 2)
void attn_kernel(const float* __restrict__ x,
                 const unsigned short* __restrict__ wz,
                 float* __restrict__ out) {
  __shared__ unsigned short wf[3 * 16 * 64 * 8];  // 48 KiB: all weight B-fragments, staged once
  __shared__ unsigned short qs[64 * QSTR];        // q rows (wave-private); reused for P
  __shared__ unsigned short ks_[64 * QSTR];       // k row-major [t][h]
  __shared__ unsigned short vts[64 * QSTR];       // v transposed [h][t]

  const int tid  = threadIdx.x;
  const int wave = tid >> 6;
  const int lane = tid & 63;
  const int quad = lane >> 4;
  const int l15  = lane & 15;
  const int mbase = wave * 16;
  const float scale = 0.08838834764831845f;  // 128^-0.5 (embed dim, per reference)
  const int b0 = blockIdx.x * BPB;

  // ---- one-time: stage all weight fragments into LDS (flat copy, 16 B/thread x12)
  #pragma unroll
  for (int j = 0; j < 12; ++j) {
    int idx = j * 256 + tid;                 // 16B chunk index, [0, 3072)
    *(uint4*)&wf[idx * 8] = *(const uint4*)(wz + (size_t)idx * 8);
  }

  // ---- prefetch x for batch 0
  f32x4 raw[8];
  {
    const float* xr = x + ((size_t)b0 * TT + mbase + l15) * CC + quad * 8;
    #pragma unroll
    for (int ksi = 0; ksi < 4; ++ksi) {
      raw[2 * ksi]     = *(const f32x4*)(xr + ksi * 32);
      raw[2 * ksi + 1] = *(const f32x4*)(xr + ksi * 32 + 4);
    }
  }

  __syncthreads();   // wf ready (also covers raw ordering trivially)

  for (int bi = 0; bi < BPB; ++bi) {
    const int b = b0 + bi;

    // ---- convert prefetched x to bf16 A-fragments: A[m=l15][k=quad*8+j]
    bf16x8 xfrag[4];
    #pragma unroll
    for (int ksi = 0; ksi < 4; ++ksi) {
      bf16x8 f;
      #pragma unroll
      for (int j = 0; j < 4; ++j) {
        union { unsigned short u; __bf16 b; } cv;
        cv.u = f2bf(raw[2 * ksi][j]);     f[j]     = cv.b;
        cv.u = f2bf(raw[2 * ksi + 1][j]); f[j + 4] = cv.b;
      }
      xfrag[ksi] = f;
    }

    // ---- issue next batch's x loads (in flight across this batch's compute)
    if (bi < BPB - 1) {
      const float* xr = x + ((size_t)(b + 1) * TT + mbase + l15) * CC + quad * 8;
      #pragma unroll
      for (int ksi = 0; ksi < 4; ++ksi) {
        raw[2 * ksi]     = *(const f32x4*)(xr + ksi * 32);
        raw[2 * ksi + 1] = *(const f32x4*)(xr + ksi * 32 + 4);
      }
    }

    if (bi > 0) __syncthreads();   // all waves done reading ks_/vts of previous batch

    // ---- Phase 1: q, k, v projections; B-fragments from wf (ds_read_b128, lane*16)
    #pragma unroll
    for (int mat = 0; mat < 3; ++mat) {
      #pragma unroll
      for (int nt = 0; nt < 4; ++nt) {
        f32x4 acc = {0.f, 0.f, 0.f, 0.f};
        #pragma unroll
        for (int ksi = 0; ksi < 4; ++ksi) {
          bf16x8 bfrag = *(const bf16x8*)&wf[(((mat * 4 + nt) * 4 + ksi) * 64 + lane) * 8];
          acc = __builtin_amdgcn_mfma_f32_16x16x32_bf16(xfrag[ksi], bfrag, acc, 0, 0, 0);
        }
        // C/D: col = nt*16 + l15, row = mbase + quad*4 + r
        #pragma unroll
        for (int r = 0; r < 4; ++r) {
          int row = mbase + quad * 4 + r;
          int col = nt * 16 + l15;
          unsigned short v = f2bf(acc[r]);
          if (mat == 0)      qs[row * QSTR + col] = v;
          else if (mat == 1) ks_[row * QSTR + col] = v;
          else               vts[col * QSTR + row] = v;   // v stored transposed
        }
      }
    }
    __syncthreads();   // k, vT (cross-wave) ready

    // ---- Phase 2: S = q k^T * scale, causal mask, softmax -> P into qs (wave-private)
    f32x4 sc[4];
    {
      bf16x8 aq[2];
      #pragma unroll
      for (int k2 = 0; k2 < 2; ++k2)
        aq[k2] = *(const bf16x8*)&qs[(mbase + l15) * QSTR + k2 * 32 + quad * 8];
      #pragma unroll
      for (int nt = 0; nt < 4; ++nt) {
        f32x4 acc = {0.f, 0.f, 0.f, 0.f};
        #pragma unroll
        for (int k2 = 0; k2 < 2; ++k2) {
          bf16x8 bk = *(const bf16x8*)&ks_[(nt * 16 + l15) * QSTR + k2 * 32 + quad * 8];
          acc = __builtin_amdgcn_mfma_f32_16x16x32_bf16(aq[k2], bk, acc, 0, 0, 0);
        }
        sc[nt] = acc;
      }
    }
    #pragma unroll
    for (int r = 0; r < 4; ++r) {
      int row = mbase + quad * 4 + r;
      float vals[4];
      #pragma unroll
      for (int nt = 0; nt < 4; ++nt) {
        int col = nt * 16 + l15;
        float v = sc[nt][r] * scale;
        vals[nt] = (col <= row) ? v : -__builtin_inff();
      }
      float m = fmaxf(fmaxf(vals[0], vals[1]), fmaxf(vals[2], vals[3]));
      #pragma unroll
      for (int d = 1; d < 16; d <<= 1) m = fmaxf(m, __shfl_xor(m, d, 64));
      float s = 0.f;
      #pragma unroll
      for (int nt = 0; nt < 4; ++nt) { vals[nt] = __expf(vals[nt] - m); s += vals[nt]; }
      #pragma unroll
      for (int d = 1; d < 16; d <<= 1) s += __shfl_xor(s, d, 64);
      float inv = 1.f / s;
      // P overwrites this wave's own q rows; rows are wave-private -> no barrier
      #pragma unroll
      for (int nt = 0; nt < 4; ++nt)
        qs[row * QSTR + nt * 16 + l15] = f2bf(vals[nt] * inv);
    }

    // ---- Phase 3: O = P @ V
    bf16x8 ap[2];
    #pragma unroll
    for (int k2 = 0; k2 < 2; ++k2)
      ap[k2] = *(const bf16x8*)&qs[(mbase + l15) * QSTR + k2 * 32 + quad * 8];
    float* ob = out + ((size_t)b * TT) * HH;
    #pragma unroll
    for (int nt = 0; nt < 4; ++nt) {
      f32x4 acc = {0.f, 0.f, 0.f, 0.f};
      #pragma unroll
      for (int k2 = 0; k2 < 2; ++k2) {
        bf16x8 bv = *(const bf16x8*)&vts[(nt * 16 + l15) * QSTR + k2 * 32 + quad * 8];
        acc = __builtin_amdgcn_mfma_f32_16x16x32_bf16(ap[k2], bv, acc, 0, 0, 0);
      }
      #pragma unroll
      for (int r = 0; r < 4; ++r) {
        int row = mbase + quad * 4 + r;
        ob[row * HH + nt * 16 + l15] = acc[r];   // fp32 store
      }
    }
  }
}

extern "C" void kernel_launch(void* const* d_in, const int* in_sizes, int n_in,
                              void* d_out, int out_size, void* d_ws, size_t ws_size,
                              hipStream_t stream) {
  const float* x  = (const float*)d_in[0];
  const float* Wq = (const float*)d_in[1];
  const float* Wk = (const float*)d_in[2];
  const float* Wv = (const float*)d_in[3];
  unsigned short* wz = (unsigned short*)d_ws;   // 3*16*64*8 bf16 = 48 KiB scratch
  float* outp = (float*)d_out;

  swizzle_w_kernel<<<(3 * 16 * 64 + 255) / 256, 256, 0, stream>>>(Wq, Wk, Wv, wz);
  attn_kernel<<<NB / BPB, 256, 0, stream>>>(x, wz, outp);
}